// Round 6
// baseline (866.247 us; speedup 1.0000x reference)
//
#include <hip/hip_runtime.h>
#include <math.h>

// PraxisNano: B=4, T=8192, H=512, E=2048, C=64, stride=32
// Inputs: float32. Output: float32. Internal: bf16 MFMA, __sinf.
// GEMM: BM=256/BN=128/BK=64, 512 thr (8 waves 4Mx2N, per-wave 64x64),
// TRIPLE-buffered LDS, 4-phase-per-K-tile interleave (m201 template adapted):
// per phase {stage 1 unit of tile t+2 | ds_read quadrant frags | s_barrier |
// lgkmcnt(0) | setprio(1) | 8 MFMA | setprio(0) | s_barrier}; counted
// s_waitcnt vmcnt(6) ONLY at tile boundary (stage lead = 2 tiles -> never
// drains). T2 both-sides XOR swizzle (r4: conflicts==0). T1 XCD swizzle.
#define TB 4
#define TT 8192
#define TH 512
#define TE 2048
#define NCHUNK 256
#define GCTOT 1024          // TB*NCHUNK

typedef unsigned short u16;
typedef short bf8v __attribute__((ext_vector_type(8)));   // 8 bf16 MFMA frag
typedef float f4v __attribute__((ext_vector_type(4)));    // MFMA accumulator

__device__ __forceinline__ float bu2f(u16 u) {
    unsigned int x = ((unsigned int)u) << 16; float f; __builtin_memcpy(&f, &x, 4); return f;
}
__device__ __forceinline__ u16 f2bu(float f) {
    unsigned int x; __builtin_memcpy(&x, &f, 4);
    x = x + 0x7fffu + ((x >> 16) & 1u);   // RNE
    return (u16)(x >> 16);
}

// ---------------- composite TriLinear matrix, transposed: Mt[s][t] = ((W2.tri)(W1.tri))[t][s]
__global__ __launch_bounds__(256) void make_Mt(const float* __restrict__ W1,
                                               const float* __restrict__ W2,
                                               float* __restrict__ Mt) {
    __shared__ float w1[64 * 64];
    __shared__ float w2[64 * 64];
    for (int i = threadIdx.x; i < 4096; i += 256) { w1[i] = W1[i]; w2[i] = W2[i]; }
    __syncthreads();
    for (int i = threadIdx.x; i < 4096; i += 256) {
        int t = i >> 6, s = i & 63;
        float a = 0.f;
        if (t >= s) for (int k = s; k <= t; ++k) a += w2[t * 64 + k] * w1[k * 64 + s];
        Mt[s * 64 + t] = a;
    }
}

// ---------------- transpose f32 (R x C) -> bf16 (C x R)
__global__ __launch_bounds__(256) void transpose_b(const float* __restrict__ in,
                                                   u16* __restrict__ out, int R, int C) {
    __shared__ u16 tile[64][65];
    const int bx = blockIdx.x, by = blockIdx.y;
    const int tx = threadIdx.x & 63, ty = threadIdx.x >> 6;
#pragma unroll
    for (int i = 0; i < 16; ++i) {
        int r = ty + i * 4;
        tile[r][tx] = f2bu(in[(size_t)(by * 64 + r) * C + bx * 64 + tx]);
    }
    __syncthreads();
#pragma unroll
    for (int i = 0; i < 16; ++i) {
        int r = ty + i * 4;
        out[(size_t)(bx * 64 + r) * R + by * 64 + tx] = tile[tx][r];
    }
}

// ---------------- LN1 stats per x-row (mean, rstd)
__global__ __launch_bounds__(256) void ln_stats(const float* __restrict__ x,
                                                float2* __restrict__ st) {
    const int wave = threadIdx.x >> 6, lane = threadIdx.x & 63;
    const size_t row = (size_t)blockIdx.x * 4 + wave;
    const float4* p = (const float4*)(x + row * TH);
    float4 a = p[lane * 2], b = p[lane * 2 + 1];
    float s = 0.f, q = 0.f;
    float v[8] = {a.x, a.y, a.z, a.w, b.x, b.y, b.z, b.w};
#pragma unroll
    for (int i = 0; i < 8; ++i) { s += v[i]; q += v[i] * v[i]; }
#pragma unroll
    for (int o = 32; o; o >>= 1) { s += __shfl_xor(s, o); q += __shfl_xor(q, o); }
    const float mean = s * (1.f / TH);
    float var = q * (1.f / TH) - mean * mean;
    if (var < 0.f) var = 0.f;
    if (lane == 0) st[row] = make_float2(mean, rsqrtf(var + 1e-5f));
}

// ---------------- LN2: bf16 rows in -> bf16 rows out, f32 gamma/beta
__global__ __launch_bounds__(256) void ln_rows(const u16* __restrict__ in,
                                               u16* __restrict__ out,
                                               const float* __restrict__ g,
                                               const float* __restrict__ b) {
    const int wave = threadIdx.x >> 6, lane = threadIdx.x & 63;
    const size_t row = (size_t)blockIdx.x * 4 + wave;
    uint4 raw = *((const uint4*)(in + row * TH) + lane);
    const u16* e = (const u16*)&raw;
    float v[8]; float s = 0.f, q = 0.f;
#pragma unroll
    for (int i = 0; i < 8; ++i) { v[i] = bu2f(e[i]); s += v[i]; q += v[i] * v[i]; }
#pragma unroll
    for (int o = 32; o; o >>= 1) { s += __shfl_xor(s, o); q += __shfl_xor(q, o); }
    const float mean = s * (1.f / TH);
    float var = q * (1.f / TH) - mean * mean;
    if (var < 0.f) var = 0.f;
    const float rstd = rsqrtf(var + 1e-5f);
    float4 g0 = ((const float4*)g)[lane * 2], g1 = ((const float4*)g)[lane * 2 + 1];
    float4 b0 = ((const float4*)b)[lane * 2], b1 = ((const float4*)b)[lane * 2 + 1];
    float ge[8] = {g0.x, g0.y, g0.z, g0.w, g1.x, g1.y, g1.z, g1.w};
    float be[8] = {b0.x, b0.y, b0.z, b0.w, b1.x, b1.y, b1.z, b1.w};
    u16 ov[8];
#pragma unroll
    for (int i = 0; i < 8; ++i) ov[i] = f2bu((v[i] - mean) * rstd * ge[i] + be[i]);
    *((uint4*)(out + row * TH) + lane) = *(uint4*)ov;
}

// ---------------- TriLinear for one slice (global-chunk indexed), LN1 fused via stats
__global__ __launch_bounds__(256) void trilinear_f(const float* __restrict__ x,
                                                   const float2* __restrict__ st,
                                                   const float* __restrict__ g,
                                                   const float* __restrict__ bb,
                                                   const float* __restrict__ Mt,
                                                   u16* __restrict__ c2s,
                                                   int gc0) {
    const int ln = blockIdx.x;
    const int gc = gc0 + ln;
    const int b = gc >> 8, n = gc & 255;
    const int h = (blockIdx.y << 8) + threadIdx.x;
    const int base = n * 32;
    const float gh = g[h], bh = bb[h];
    float acc[64];
#pragma unroll
    for (int t = 0; t < 64; ++t) acc[t] = 0.f;
    for (int s = 0; s < 64; ++s) {
        int pos = base + s; if (pos > TT - 1) pos = TT - 1;
        const size_t ro = (size_t)b * TT + pos;
        const float2 mr = st[ro];
        const float cn = (x[ro * TH + h] - mr.x) * mr.y * gh + bh;
        const float* m = Mt + s * 64;
#pragma unroll
        for (int t = 0; t < 64; ++t) acc[t] += m[t] * cn;
    }
#pragma unroll
    for (int t = 0; t < 64; ++t) {
        int pos = base + t; if (pos > TT - 1) pos = TT - 1;
        const float resid = x[((size_t)b * TT + pos) * TH + h];
        c2s[(size_t)(ln * 64 + t) * TH + h] = f2bu(acc[t] + resid);
    }
}

// ---------------- 4-phase interleaved MFMA GEMM, B^T input. BM=256, BN=128, BK=64.
// 512 threads = 8 waves (4M x 2N); per-wave C: 64 x 64 (acc[4][4]).
// Staging (verbatim r5, verified): srow=tid>>3, SOURCE chunk (tid&7)^(srow&7)
// -> LDS[r][c]=G[r][c^(r&7)]; read offset (ks+fq)^s8. Conflicts==0 (r4 PMC).
// Stage units per tile: U0=A rows[0,128) (2 loads), U1=A[128,256) (2),
// U2=B[0,64) (1), U3=B[64,128) (1). Phase p of tile t stages unit p of t+2
// into buf (t+2)%3 (readers passed barrier at end of t-1 -> WAR safe).
// Tile-boundary wait vmcnt(6): tile t+1 staged during t-1 -> confirmed;
// only t+2's 6 loads stay in flight. Never drains mid-loop (T4).
// MODE 1: C = __sinf(acc + bias);  MODE 2: C = acc + bias + addp
template <int MODE>
__global__ __launch_bounds__(512, 2) void gemm_ph(const u16* __restrict__ A,    // M x K bf16
                                                  const u16* __restrict__ Bt,   // N x K bf16
                                                  u16* __restrict__ C,          // M x N bf16
                                                  const float* __restrict__ bias,
                                                  const u16* __restrict__ addp,
                                                  int N, int K) {
    __shared__ __attribute__((aligned(16))) u16 lA[3][256 * 64];   // 96 KiB
    __shared__ __attribute__((aligned(16))) u16 lB[3][128 * 64];   // 48 KiB
    const int tid = threadIdx.x;
    const int wave = tid >> 6;             // 0..7
    const int lane = tid & 63;
    const int wr = wave >> 1;              // 0..3 (M)
    const int wc = wave & 1;               // 0..1 (N)
    const int fr = lane & 15;
    const int fq = (lane >> 4) << 3;       // 0,8,16,24 (u16)
    const int s8 = (fr & 7) << 3;          // swizzle XOR (u16)

    // T1: XCD-chunked block swizzle (bijective when nwg%8==0)
    int bx = blockIdx.x, by = blockIdx.y;
    const int gx = gridDim.x;
    const int nwg = gx * (int)gridDim.y;
    if ((nwg & 7) == 0) {
        const int bid = by * gx + bx;
        const int swz = (bid & 7) * (nwg >> 3) + (bid >> 3);
        bx = swz % gx; by = swz / gx;
    }
    const int bm = by << 8;
    const int bn = bx << 7;

    // staging addresses: row srow (+i*64), source chunk XOR'ed by row&7
    const int srow = tid >> 3;                          // 0..63
    const int gch = ((tid & 7) ^ (srow & 7)) << 3;      // u16 offset
    const u16* pa = A + (size_t)(bm + srow) * K + gch;
    const u16* pb = Bt + (size_t)(bn + srow) * K + gch;
    const int ldsw = wave << 9;                         // wave-uniform base (u16)

    const int NT = K >> 6;
    f4v acc[4][4] = {};

    auto stageA = [&](int t, int buf2, int i) {
        __builtin_amdgcn_global_load_lds(
            (const __attribute__((address_space(1))) void*)(pa + (size_t)(i * 64) * K + ((size_t)t << 6)),
            (__attribute__((address_space(3))) void*)(&lA[buf2][(i << 12) + ldsw]), 16, 0, 0);
    };
    auto stageB = [&](int t, int buf2, int i) {
        __builtin_amdgcn_global_load_lds(
            (const __attribute__((address_space(1))) void*)(pb + (size_t)(i * 64) * K + ((size_t)t << 6)),
            (__attribute__((address_space(3))) void*)(&lB[buf2][(i << 12) + ldsw]), 16, 0, 0);
    };

    // prologue: tiles 0,1 fully in flight (12 loads); confirm tile 0 (counted).
    stageA(0, 0, 0); stageA(0, 0, 1); stageA(0, 0, 2); stageA(0, 0, 3);
    stageB(0, 0, 0); stageB(0, 0, 1);
    stageA(1, 1, 0); stageA(1, 1, 1); stageA(1, 1, 2); stageA(1, 1, 3);
    stageB(1, 1, 0); stageB(1, 1, 1);
    asm volatile("s_waitcnt vmcnt(6)" ::: "memory");
    asm volatile("s_barrier" ::: "memory");

    const int arow0 = (wr << 6) + fr;      // + mi*16
    const int brow0 = (wc << 6) + fr;      // + ni*16
    const int c0 = fq ^ s8;                // slice ks=0 swizzled col (u16)
    const int c1 = (32 + fq) ^ s8;         // slice ks=32 (XOR on chunk bits)

    int buf = 0;
    for (int t = 0; t < NT; ++t) {
        const u16* la = lA[buf];
        const u16* lb = lB[buf];
        int sb = buf + 2; if (sb >= 3) sb -= 3;
        const bool pre = (t + 2 < NT);

        bf8v bfr[4][2];    // all B frags, held for the whole tile
        bf8v a0[2][2];     // A low half (mi 0,1)
        bf8v a1[2][2];     // A high half (mi 2,3)

        // ---- phase 0: stage U0 | read B(8) + A-low(4) | barrier | MFMA q(0,0)
        if (pre) { stageA(t + 2, sb, 0); stageA(t + 2, sb, 1); }
#pragma unroll
        for (int ni = 0; ni < 4; ++ni) {
            bfr[ni][0] = *(const bf8v*)(lb + ((brow0 + (ni << 4)) << 6) + c0);
            bfr[ni][1] = *(const bf8v*)(lb + ((brow0 + (ni << 4)) << 6) + c1);
        }
#pragma unroll
        for (int mi = 0; mi < 2; ++mi) {
            a0[mi][0] = *(const bf8v*)(la + ((arow0 + (mi << 4)) << 6) + c0);
            a0[mi][1] = *(const bf8v*)(la + ((arow0 + (mi << 4)) << 6) + c1);
        }
        asm volatile("s_barrier" ::: "memory");
        asm volatile("s_waitcnt lgkmcnt(0)" ::: "memory");
        __builtin_amdgcn_s_setprio(1);
#pragma unroll
        for (int mi = 0; mi < 2; ++mi)
#pragma unroll
            for (int ni = 0; ni < 2; ++ni) {
                acc[mi][ni] = __builtin_amdgcn_mfma_f32_16x16x32_bf16(a0[mi][0], bfr[ni][0], acc[mi][ni], 0, 0, 0);
                acc[mi][ni] = __builtin_amdgcn_mfma_f32_16x16x32_bf16(a0[mi][1], bfr[ni][1], acc[mi][ni], 0, 0, 0);
            }
        __builtin_amdgcn_s_setprio(0);
        asm volatile("s_barrier" ::: "memory");

        // ---- phase 1: stage U1 | (regs held) | MFMA q(0,1)
        if (pre) { stageA(t + 2, sb, 2); stageA(t + 2, sb, 3); }
        asm volatile("s_barrier" ::: "memory");
        __builtin_amdgcn_s_setprio(1);
#pragma unroll
        for (int mi = 0; mi < 2; ++mi)
#pragma unroll
            for (int ni = 0; ni < 2; ++ni) {
                acc[mi][ni + 2] = __builtin_amdgcn_mfma_f32_16x16x32_bf16(a0[mi][0], bfr[ni + 2][0], acc[mi][ni + 2], 0, 0, 0);
                acc[mi][ni + 2] = __builtin_amdgcn_mfma_f32_16x16x32_bf16(a0[mi][1], bfr[ni + 2][1], acc[mi][ni + 2], 0, 0, 0);
            }
        __builtin_amdgcn_s_setprio(0);
        asm volatile("s_barrier" ::: "memory");

        // ---- phase 2: stage U2 | read A-high(4) | barrier | MFMA q(1,0)
        if (pre) stageB(t + 2, sb, 0);
#pragma unroll
        for (int mi = 0; mi < 2; ++mi) {
            a1[mi][0] = *(const bf8v*)(la + ((arow0 + ((mi + 2) << 4)) << 6) + c0);
            a1[mi][1] = *(const bf8v*)(la + ((arow0 + ((mi + 2) << 4)) << 6) + c1);
        }
        asm volatile("s_barrier" ::: "memory");
        asm volatile("s_waitcnt lgkmcnt(0)" ::: "memory");
        __builtin_amdgcn_s_setprio(1);
#pragma unroll
        for (int mi = 0; mi < 2; ++mi)
#pragma unroll
            for (int ni = 0; ni < 2; ++ni) {
                acc[mi + 2][ni] = __builtin_amdgcn_mfma_f32_16x16x32_bf16(a1[mi][0], bfr[ni][0], acc[mi + 2][ni], 0, 0, 0);
                acc[mi + 2][ni] = __builtin_amdgcn_mfma_f32_16x16x32_bf16(a1[mi][1], bfr[ni][1], acc[mi + 2][ni], 0, 0, 0);
            }
        __builtin_amdgcn_s_setprio(0);
        asm volatile("s_barrier" ::: "memory");

        // ---- phase 3: stage U3 | MFMA q(1,1) | counted tile-boundary wait
        if (pre) stageB(t + 2, sb, 1);
        asm volatile("s_barrier" ::: "memory");
        __builtin_amdgcn_s_setprio(1);
#pragma unroll
        for (int mi = 0; mi < 2; ++mi)
#pragma unroll
            for (int ni = 0; ni < 2; ++ni) {
                acc[mi + 2][ni + 2] = __builtin_amdgcn_mfma_f32_16x16x32_bf16(a1[mi][0], bfr[ni + 2][0], acc[mi + 2][ni + 2], 0, 0, 0);
                acc[mi + 2][ni + 2] = __builtin_amdgcn_mfma_f32_16x16x32_bf16(a1[mi][1], bfr[ni + 2][1], acc[mi + 2][ni + 2], 0, 0, 0);
            }
        __builtin_amdgcn_s_setprio(0);
        if (pre)                asm volatile("s_waitcnt vmcnt(6)" ::: "memory");
        else if (t + 1 < NT)    asm volatile("s_waitcnt vmcnt(0)" ::: "memory");
        asm volatile("s_barrier" ::: "memory");

        buf = buf + 1; if (buf >= 3) buf -= 3;
    }

    // ---- epilogue: C/D layout col=lane&15, row=(lane>>4)*4+r (m89/m91)
    const int rq = (lane >> 4) << 2;
#pragma unroll
    for (int mi = 0; mi < 4; ++mi) {
#pragma unroll
        for (int ni = 0; ni < 4; ++ni) {
            const int col = bn + (wc << 6) + (ni << 4) + fr;
            const float bv = bias[col];
#pragma unroll
            for (int r = 0; r < 4; ++r) {
                const int row = bm + (wr << 6) + (mi << 4) + rq + r;
                float v = acc[mi][ni][r] + bv;
                if (MODE == 1) v = __sinf(v);
                else v += bu2f(addp[(size_t)row * N + col]);
                C[(size_t)row * N + col] = f2bu(v);
            }
        }
    }
}

// ---------------- per-slice gather -> FLOAT32 output (linear position mapping)
__global__ __launch_bounds__(256) void gather_slice(const u16* __restrict__ ocs,
                                                    const u16* __restrict__ carry,
                                                    float* __restrict__ out,
                                                    int gc0) {
    const int idx = blockIdx.x * 256 + threadIdx.x;   // vec8 id within slice
    const int h8 = idx & 63;                          // TH/8
    const int prow = idx >> 6;                        // 0 .. SC*32-1
    const int ap = gc0 * 32 + prow;                   // linear (b,t) position index
    const int b = ap >> 13, t = ap & 8191;
    const int n = t >> 5, c = t & 31;
    const int ln = (b << 8) + n - gc0;                // covering chunk, slice-local
    uint4 r1 = *((const uint4*)ocs + (size_t)(ln * 64 + c) * 64 + h8);
    const u16* e1 = (const u16*)&r1;
    float ov[8];
    if (t < 32) {
#pragma unroll
        for (int i = 0; i < 8; ++i) ov[i] = bu2f(e1[i]);
    } else {
        uint4 r0;
        if (ln == 0) r0 = *((const uint4*)carry + (size_t)(c + 32) * 64 + h8);
        else         r0 = *((const uint4*)ocs + (size_t)((ln - 1) * 64 + c + 32) * 64 + h8);
        const u16* e0 = (const u16*)&r0;
#pragma unroll
        for (int i = 0; i < 8; ++i) ov[i] = 0.5f * (bu2f(e1[i]) + bu2f(e0[i]));
    }
    float4* dst = (float4*)(out + (size_t)ap * TH + h8 * 8);
    dst[0] = make_float4(ov[0], ov[1], ov[2], ov[3]);
    dst[1] = make_float4(ov[4], ov[5], ov[6], ov[7]);
}

// ---------------- save last chunk of slice for next slice's boundary
__global__ __launch_bounds__(256) void save_carry(const u16* __restrict__ ocs,
                                                  u16* __restrict__ carry, int SC) {
    const int i = blockIdx.x * 256 + threadIdx.x;     // uint4 id, 4096 total
    ((uint4*)carry)[i] = ((const uint4*)(ocs + (size_t)(SC - 1) * 64 * TH))[i];
}

extern "C" void kernel_launch(void* const* d_in, const int* in_sizes, int n_in,
                              void* d_out, int out_size, void* d_ws, size_t ws_size,
                              hipStream_t stream) {
    const float* x   = (const float*)d_in[0];
    const float* g1  = (const float*)d_in[1];
    const float* b1  = (const float*)d_in[2];
    const float* W1  = (const float*)d_in[3];
    const float* W2  = (const float*)d_in[4];
    const float* g2  = (const float*)d_in[5];
    const float* b2  = (const float*)d_in[6];
    const float* fw1 = (const float*)d_in[7];
    const float* fb1 = (const float*)d_in[8];
    const float* fw2 = (const float*)d_in[9];
    const float* fb2 = (const float*)d_in[10];
    float* out = (float*)d_out;
    char* ws = (char*)d_ws;

    size_t o = 0;
    auto take = [&](size_t n) { size_t r = o; o = (o + n + 255) & ~(size_t)255; return r; };
    float*  Mt    = (float*) (ws + take(64 * 64 * 4));
    u16*    f1t   = (u16*)   (ws + take((size_t)TE * TH * 2));
    u16*    f2t   = (u16*)   (ws + take((size_t)TH * TE * 2));
    float2* st1   = (float2*)(ws + take((size_t)TB * TT * 8));
    u16*    carry = (u16*)   (ws + take((size_t)64 * TH * 2));
    const size_t fixed = o;

    // Adaptive slice size (global chunks per slice). Min 4 so SR is a multiple
    // of 256 (gemm_ph uses 256-row tiles); cap 256 so us stays L3-resident.
    int SC = 4;
    for (int cand = 256; cand >= 4; cand >>= 1) {
        size_t per = (size_t)cand * 64 * (TH * 2 * 3 + TE * 2) + 4 * 256;
        if (fixed + per <= ws_size) { SC = cand; break; }
    }
    u16* c2s = (u16*)(ws + take((size_t)SC * 64 * TH * 2));
    u16* h2s = (u16*)(ws + take((size_t)SC * 64 * TH * 2));
    u16* ocs = (u16*)(ws + take((size_t)SC * 64 * TH * 2));
    u16* us  = (u16*)(ws + take((size_t)SC * 64 * TE * 2));
    const int SR = SC * 64;

    make_Mt<<<1, 256, 0, stream>>>(W1, W2, Mt);
    transpose_b<<<dim3(TE / 64, TH / 64), 256, 0, stream>>>(fw1, f1t, TH, TE);
    transpose_b<<<dim3(TH / 64, TE / 64), 256, 0, stream>>>(fw2, f2t, TE, TH);
    ln_stats<<<(TB * TT) / 4, 256, 0, stream>>>(x, st1);

    for (int gc0 = 0; gc0 < GCTOT; gc0 += SC) {
        trilinear_f<<<dim3(SC, TH / 256), 256, 0, stream>>>(x, st1, g1, b1, Mt, c2s, gc0);
        ln_rows<<<SR / 4, 256, 0, stream>>>(c2s, h2s, g2, b2);
        gemm_ph<1><<<dim3(TE / 128, SR / 256), 512, 0, stream>>>(
            h2s, f1t, us, fb1, (const u16*)nullptr, TE, TH);
        gemm_ph<2><<<dim3(TH / 128, SR / 256), 512, 0, stream>>>(
            us, f2t, ocs, fb2, c2s, TH, TE);
        gather_slice<<<SC * 8, 256, 0, stream>>>(ocs, carry, out, gc0);
        save_carry<<<16, 256, 0, stream>>>(ocs, carry, SC);
    }
}

// Round 7
// 790.073 us; speedup vs baseline: 1.0964x; 1.0964x over previous
//
#include <hip/hip_runtime.h>
#include <math.h>

// PraxisNano: B=4, T=8192, H=512, E=2048, C=64, stride=32
// Inputs: float32. Output: float32. Internal: bf16 MFMA, __sinf.
// GEMM r7: BM=256/BN=256/BK=64, 512 thr (8 waves 2Mx4N, per-wave 128x64 =
// fragment-reuse 5.33, the m201 geometry). Double-buffered 128 KiB LDS;
// per-iter: reads -> lgkmcnt(0) -> barrier -> stage(t+2 -> freed buf) ->
// setprio+64 MFMA -> counted vmcnt(8) -> barrier (lead-2, never drains
// mid-loop). T2 both-sides XOR swizzle (r4 PMC: conflicts==0). T1 XCD swizzle.
#define TB 4
#define TT 8192
#define TH 512
#define TE 2048
#define NCHUNK 256
#define GCTOT 1024          // TB*NCHUNK

typedef unsigned short u16;
typedef short bf8v __attribute__((ext_vector_type(8)));   // 8 bf16 MFMA frag
typedef float f4v __attribute__((ext_vector_type(4)));    // MFMA accumulator

__device__ __forceinline__ float bu2f(u16 u) {
    unsigned int x = ((unsigned int)u) << 16; float f; __builtin_memcpy(&f, &x, 4); return f;
}
__device__ __forceinline__ u16 f2bu(float f) {
    unsigned int x; __builtin_memcpy(&x, &f, 4);
    x = x + 0x7fffu + ((x >> 16) & 1u);   // RNE
    return (u16)(x >> 16);
}

// ---------------- composite TriLinear matrix, transposed: Mt[s][t] = ((W2.tri)(W1.tri))[t][s]
__global__ __launch_bounds__(256) void make_Mt(const float* __restrict__ W1,
                                               const float* __restrict__ W2,
                                               float* __restrict__ Mt) {
    __shared__ float w1[64 * 64];
    __shared__ float w2[64 * 64];
    for (int i = threadIdx.x; i < 4096; i += 256) { w1[i] = W1[i]; w2[i] = W2[i]; }
    __syncthreads();
    for (int i = threadIdx.x; i < 4096; i += 256) {
        int t = i >> 6, s = i & 63;
        float a = 0.f;
        if (t >= s) for (int k = s; k <= t; ++k) a += w2[t * 64 + k] * w1[k * 64 + s];
        Mt[s * 64 + t] = a;
    }
}

// ---------------- transpose f32 (R x C) -> bf16 (C x R)
__global__ __launch_bounds__(256) void transpose_b(const float* __restrict__ in,
                                                   u16* __restrict__ out, int R, int C) {
    __shared__ u16 tile[64][65];
    const int bx = blockIdx.x, by = blockIdx.y;
    const int tx = threadIdx.x & 63, ty = threadIdx.x >> 6;
#pragma unroll
    for (int i = 0; i < 16; ++i) {
        int r = ty + i * 4;
        tile[r][tx] = f2bu(in[(size_t)(by * 64 + r) * C + bx * 64 + tx]);
    }
    __syncthreads();
#pragma unroll
    for (int i = 0; i < 16; ++i) {
        int r = ty + i * 4;
        out[(size_t)(bx * 64 + r) * R + by * 64 + tx] = tile[tx][r];
    }
}

// ---------------- LN1 stats per x-row (mean, rstd)
__global__ __launch_bounds__(256) void ln_stats(const float* __restrict__ x,
                                                float2* __restrict__ st) {
    const int wave = threadIdx.x >> 6, lane = threadIdx.x & 63;
    const size_t row = (size_t)blockIdx.x * 4 + wave;
    const float4* p = (const float4*)(x + row * TH);
    float4 a = p[lane * 2], b = p[lane * 2 + 1];
    float s = 0.f, q = 0.f;
    float v[8] = {a.x, a.y, a.z, a.w, b.x, b.y, b.z, b.w};
#pragma unroll
    for (int i = 0; i < 8; ++i) { s += v[i]; q += v[i] * v[i]; }
#pragma unroll
    for (int o = 32; o; o >>= 1) { s += __shfl_xor(s, o); q += __shfl_xor(q, o); }
    const float mean = s * (1.f / TH);
    float var = q * (1.f / TH) - mean * mean;
    if (var < 0.f) var = 0.f;
    if (lane == 0) st[row] = make_float2(mean, rsqrtf(var + 1e-5f));
}

// ---------------- LN2: bf16 rows in -> bf16 rows out, f32 gamma/beta
__global__ __launch_bounds__(256) void ln_rows(const u16* __restrict__ in,
                                               u16* __restrict__ out,
                                               const float* __restrict__ g,
                                               const float* __restrict__ b) {
    const int wave = threadIdx.x >> 6, lane = threadIdx.x & 63;
    const size_t row = (size_t)blockIdx.x * 4 + wave;
    uint4 raw = *((const uint4*)(in + row * TH) + lane);
    const u16* e = (const u16*)&raw;
    float v[8]; float s = 0.f, q = 0.f;
#pragma unroll
    for (int i = 0; i < 8; ++i) { v[i] = bu2f(e[i]); s += v[i]; q += v[i] * v[i]; }
#pragma unroll
    for (int o = 32; o; o >>= 1) { s += __shfl_xor(s, o); q += __shfl_xor(q, o); }
    const float mean = s * (1.f / TH);
    float var = q * (1.f / TH) - mean * mean;
    if (var < 0.f) var = 0.f;
    const float rstd = rsqrtf(var + 1e-5f);
    float4 g0 = ((const float4*)g)[lane * 2], g1 = ((const float4*)g)[lane * 2 + 1];
    float4 b0 = ((const float4*)b)[lane * 2], b1 = ((const float4*)b)[lane * 2 + 1];
    float ge[8] = {g0.x, g0.y, g0.z, g0.w, g1.x, g1.y, g1.z, g1.w};
    float be[8] = {b0.x, b0.y, b0.z, b0.w, b1.x, b1.y, b1.z, b1.w};
    u16 ov[8];
#pragma unroll
    for (int i = 0; i < 8; ++i) ov[i] = f2bu((v[i] - mean) * rstd * ge[i] + be[i]);
    *((uint4*)(out + row * TH) + lane) = *(uint4*)ov;
}

// ---------------- TriLinear for one slice (global-chunk indexed), LN1 fused via stats
__global__ __launch_bounds__(256) void trilinear_f(const float* __restrict__ x,
                                                   const float2* __restrict__ st,
                                                   const float* __restrict__ g,
                                                   const float* __restrict__ bb,
                                                   const float* __restrict__ Mt,
                                                   u16* __restrict__ c2s,
                                                   int gc0) {
    const int ln = blockIdx.x;
    const int gc = gc0 + ln;
    const int b = gc >> 8, n = gc & 255;
    const int h = (blockIdx.y << 8) + threadIdx.x;
    const int base = n * 32;
    const float gh = g[h], bh = bb[h];
    float acc[64];
#pragma unroll
    for (int t = 0; t < 64; ++t) acc[t] = 0.f;
    for (int s = 0; s < 64; ++s) {
        int pos = base + s; if (pos > TT - 1) pos = TT - 1;
        const size_t ro = (size_t)b * TT + pos;
        const float2 mr = st[ro];
        const float cn = (x[ro * TH + h] - mr.x) * mr.y * gh + bh;
        const float* m = Mt + s * 64;
#pragma unroll
        for (int t = 0; t < 64; ++t) acc[t] += m[t] * cn;
    }
#pragma unroll
    for (int t = 0; t < 64; ++t) {
        int pos = base + t; if (pos > TT - 1) pos = TT - 1;
        const float resid = x[((size_t)b * TT + pos) * TH + h];
        c2s[(size_t)(ln * 64 + t) * TH + h] = f2bu(acc[t] + resid);
    }
}

// ---------------- 256x256 MFMA GEMM, B^T input, per-wave 128x64 (reuse 5.33).
// Staging (verbatim algebra from r4/r5, PMC-verified conflict-free):
// srow=tid>>3 (0..63), chunk tid&7; SOURCE chunk (tid&7)^(srow&7) ->
// LDS[r][c]=G[r][c^(r&7)]; read u16 offset (ks+fq)^s8. Issue i covers rows
// i*64; 4 issues for A (256 rows) + 4 for B = 8 loads/thread/tile.
// Schedule: dbuf; iter t: ds_read 24 frags from buf[t&1]; lgkmcnt(0);
// s_barrier (all waves done with buf) ; stage tile t+2 INTO buf (WAR-safe:
// readers just passed the barrier); 64 MFMA under setprio; s_waitcnt vmcnt(8)
// (outstanding = t+1's 8 + t+2's 8; confirms t+1, keeps t+2 in flight);
// s_barrier publishes. vmcnt(0) only at loop tail.
// MODE 1: C = __sinf(acc + bias);  MODE 2: C = acc + bias + addp
template <int MODE>
__global__ __launch_bounds__(512, 2) void gemm_w(const u16* __restrict__ A,    // M x K bf16
                                                 const u16* __restrict__ Bt,   // N x K bf16
                                                 u16* __restrict__ C,          // M x N bf16
                                                 const float* __restrict__ bias,
                                                 const u16* __restrict__ addp,
                                                 int N, int K) {
    __shared__ __attribute__((aligned(16))) u16 lA[2][256 * 64];   // 64 KiB
    __shared__ __attribute__((aligned(16))) u16 lB[2][256 * 64];   // 64 KiB
    const int tid = threadIdx.x;
    const int wave = tid >> 6;             // 0..7
    const int lane = tid & 63;
    const int wr = wave >> 2;              // 0..1 (M): rows wr*128..+128
    const int wc = wave & 3;               // 0..3 (N): cols wc*64..+64
    const int fr = lane & 15;
    const int fq = (lane >> 4) << 3;       // 0,8,16,24 (u16)
    const int s8 = (fr & 7) << 3;          // swizzle XOR (u16)

    // T1: XCD-chunked block swizzle (bijective when nwg%8==0)
    int bx = blockIdx.x, by = blockIdx.y;
    const int gx = gridDim.x;
    const int nwg = gx * (int)gridDim.y;
    if ((nwg & 7) == 0) {
        const int bid = by * gx + bx;
        const int swz = (bid & 7) * (nwg >> 3) + (bid >> 3);
        bx = swz % gx; by = swz / gx;
    }
    const int bm = by << 8;
    const int bn = bx << 8;

    // staging addresses: row srow (+i*64), source chunk XOR'ed by row&7
    const int srow = tid >> 3;                          // 0..63
    const int gch = ((tid & 7) ^ (srow & 7)) << 3;      // u16 offset
    const u16* pa = A + (size_t)(bm + srow) * K + gch;
    const u16* pb = Bt + (size_t)(bn + srow) * K + gch;
    const int ldsw = wave << 9;                         // wave-uniform base (u16)

    const int NT = K >> 6;
    f4v acc[8][4] = {};

    auto stage = [&](int t, int buf) {
        const size_t ko = (size_t)t << 6;
#pragma unroll
        for (int i = 0; i < 4; ++i)
            __builtin_amdgcn_global_load_lds(
                (const __attribute__((address_space(1))) void*)(pa + (size_t)(i * 64) * K + ko),
                (__attribute__((address_space(3))) void*)(&lA[buf][(i << 12) + ldsw]), 16, 0, 0);
#pragma unroll
        for (int i = 0; i < 4; ++i)
            __builtin_amdgcn_global_load_lds(
                (const __attribute__((address_space(1))) void*)(pb + (size_t)(i * 64) * K + ko),
                (__attribute__((address_space(3))) void*)(&lB[buf][(i << 12) + ldsw]), 16, 0, 0);
    };

    // prologue: tiles 0,1 in flight (16 loads); counted wait confirms tile 0.
    stage(0, 0);
    stage(1, 1);
    asm volatile("s_waitcnt vmcnt(8)" ::: "memory");
    asm volatile("s_barrier" ::: "memory");

    const int arow0 = (wr << 7) + fr;      // + mi*16
    const int brow0 = (wc << 6) + fr;      // + ni*16
    const int c0 = fq ^ s8;                // slice ks=0 swizzled col (u16)
    const int c1 = (32 + fq) ^ s8;         // slice ks=32 (XOR on chunk bits)

    for (int t = 0; t < NT; ++t) {
        const int buf = t & 1;
        const u16* la = lA[buf];
        const u16* lb = lB[buf];
        // ---- read ALL fragments of this tile (24 x ds_read_b128)
        bf8v af[8][2], bf[4][2];
#pragma unroll
        for (int mi = 0; mi < 8; ++mi) {
            af[mi][0] = *(const bf8v*)(la + ((arow0 + (mi << 4)) << 6) + c0);
            af[mi][1] = *(const bf8v*)(la + ((arow0 + (mi << 4)) << 6) + c1);
        }
#pragma unroll
        for (int ni = 0; ni < 4; ++ni) {
            bf[ni][0] = *(const bf8v*)(lb + ((brow0 + (ni << 4)) << 6) + c0);
            bf[ni][1] = *(const bf8v*)(lb + ((brow0 + (ni << 4)) << 6) + c1);
        }
        asm volatile("s_waitcnt lgkmcnt(0)" ::: "memory");
        __builtin_amdgcn_sched_barrier(0);
        asm volatile("s_barrier" ::: "memory");          // all waves done reading buf
        if (t + 2 < NT) stage(t + 2, buf);               // overwrite freed buffer, async
        // ---- 64 MFMA (ks0 then ks1 per acc: order matches r4/r5 numerics)
        __builtin_amdgcn_s_setprio(1);
#pragma unroll
        for (int ks = 0; ks < 2; ++ks)
#pragma unroll
            for (int mi = 0; mi < 8; ++mi)
#pragma unroll
                for (int ni = 0; ni < 4; ++ni)
                    acc[mi][ni] = __builtin_amdgcn_mfma_f32_16x16x32_bf16(af[mi][ks], bf[ni][ks], acc[mi][ni], 0, 0, 0);
        __builtin_amdgcn_s_setprio(0);
        // ---- confirm tile t+1 (counted), publish
        if (t + 1 < NT) {
            if (t + 2 < NT) asm volatile("s_waitcnt vmcnt(8)" ::: "memory");
            else            asm volatile("s_waitcnt vmcnt(0)" ::: "memory");
            asm volatile("s_barrier" ::: "memory");
        }
    }

    // ---- epilogue: C/D layout col=lane&15, row=(lane>>4)*4+r (m89/m91)
    const int rq = (lane >> 4) << 2;
#pragma unroll
    for (int mi = 0; mi < 8; ++mi) {
#pragma unroll
        for (int ni = 0; ni < 4; ++ni) {
            const int col = bn + (wc << 6) + (ni << 4) + fr;
            const float bv = bias[col];
#pragma unroll
            for (int r = 0; r < 4; ++r) {
                const int row = bm + (wr << 7) + (mi << 4) + rq + r;
                float v = acc[mi][ni][r] + bv;
                if (MODE == 1) v = __sinf(v);
                else v += bu2f(addp[(size_t)row * N + col]);
                C[(size_t)row * N + col] = f2bu(v);
            }
        }
    }
}

// ---------------- per-slice gather -> FLOAT32 output (linear position mapping)
__global__ __launch_bounds__(256) void gather_slice(const u16* __restrict__ ocs,
                                                    const u16* __restrict__ carry,
                                                    float* __restrict__ out,
                                                    int gc0) {
    const int idx = blockIdx.x * 256 + threadIdx.x;   // vec8 id within slice
    const int h8 = idx & 63;                          // TH/8
    const int prow = idx >> 6;                        // 0 .. SC*32-1
    const int ap = gc0 * 32 + prow;                   // linear (b,t) position index
    const int b = ap >> 13, t = ap & 8191;
    const int n = t >> 5, c = t & 31;
    const int ln = (b << 8) + n - gc0;                // covering chunk, slice-local
    uint4 r1 = *((const uint4*)ocs + (size_t)(ln * 64 + c) * 64 + h8);
    const u16* e1 = (const u16*)&r1;
    float ov[8];
    if (t < 32) {
#pragma unroll
        for (int i = 0; i < 8; ++i) ov[i] = bu2f(e1[i]);
    } else {
        uint4 r0;
        if (ln == 0) r0 = *((const uint4*)carry + (size_t)(c + 32) * 64 + h8);
        else         r0 = *((const uint4*)ocs + (size_t)((ln - 1) * 64 + c + 32) * 64 + h8);
        const u16* e0 = (const u16*)&r0;
#pragma unroll
        for (int i = 0; i < 8; ++i) ov[i] = 0.5f * (bu2f(e1[i]) + bu2f(e0[i]));
    }
    float4* dst = (float4*)(out + (size_t)ap * TH + h8 * 8);
    dst[0] = make_float4(ov[0], ov[1], ov[2], ov[3]);
    dst[1] = make_float4(ov[4], ov[5], ov[6], ov[7]);
}

// ---------------- save last chunk of slice for next slice's boundary
__global__ __launch_bounds__(256) void save_carry(const u16* __restrict__ ocs,
                                                  u16* __restrict__ carry, int SC) {
    const int i = blockIdx.x * 256 + threadIdx.x;     // uint4 id, 4096 total
    ((uint4*)carry)[i] = ((const uint4*)(ocs + (size_t)(SC - 1) * 64 * TH))[i];
}

extern "C" void kernel_launch(void* const* d_in, const int* in_sizes, int n_in,
                              void* d_out, int out_size, void* d_ws, size_t ws_size,
                              hipStream_t stream) {
    const float* x   = (const float*)d_in[0];
    const float* g1  = (const float*)d_in[1];
    const float* b1  = (const float*)d_in[2];
    const float* W1  = (const float*)d_in[3];
    const float* W2  = (const float*)d_in[4];
    const float* g2  = (const float*)d_in[5];
    const float* b2  = (const float*)d_in[6];
    const float* fw1 = (const float*)d_in[7];
    const float* fb1 = (const float*)d_in[8];
    const float* fw2 = (const float*)d_in[9];
    const float* fb2 = (const float*)d_in[10];
    float* out = (float*)d_out;
    char* ws = (char*)d_ws;

    size_t o = 0;
    auto take = [&](size_t n) { size_t r = o; o = (o + n + 255) & ~(size_t)255; return r; };
    float*  Mt    = (float*) (ws + take(64 * 64 * 4));
    u16*    f1t   = (u16*)   (ws + take((size_t)TE * TH * 2));
    u16*    f2t   = (u16*)   (ws + take((size_t)TH * TE * 2));
    float2* st1   = (float2*)(ws + take((size_t)TB * TT * 8));
    u16*    carry = (u16*)   (ws + take((size_t)64 * TH * 2));
    const size_t fixed = o;

    // Adaptive slice size (global chunks per slice). Min 4 so SR is a multiple
    // of 256 (gemm_w uses 256-row tiles); cap 256 so us stays L3-resident.
    int SC = 4;
    for (int cand = 256; cand >= 4; cand >>= 1) {
        size_t per = (size_t)cand * 64 * (TH * 2 * 3 + TE * 2) + 4 * 256;
        if (fixed + per <= ws_size) { SC = cand; break; }
    }
    u16* c2s = (u16*)(ws + take((size_t)SC * 64 * TH * 2));
    u16* h2s = (u16*)(ws + take((size_t)SC * 64 * TH * 2));
    u16* ocs = (u16*)(ws + take((size_t)SC * 64 * TH * 2));
    u16* us  = (u16*)(ws + take((size_t)SC * 64 * TE * 2));
    const int SR = SC * 64;

    make_Mt<<<1, 256, 0, stream>>>(W1, W2, Mt);
    transpose_b<<<dim3(TE / 64, TH / 64), 256, 0, stream>>>(fw1, f1t, TH, TE);
    transpose_b<<<dim3(TH / 64, TE / 64), 256, 0, stream>>>(fw2, f2t, TE, TH);
    ln_stats<<<(TB * TT) / 4, 256, 0, stream>>>(x, st1);

    for (int gc0 = 0; gc0 < GCTOT; gc0 += SC) {
        trilinear_f<<<dim3(SC, TH / 256), 256, 0, stream>>>(x, st1, g1, b1, Mt, c2s, gc0);
        ln_rows<<<SR / 4, 256, 0, stream>>>(c2s, h2s, g2, b2);
        gemm_w<1><<<dim3(TE / 256, SR / 256), 512, 0, stream>>>(
            h2s, f1t, us, fb1, (const u16*)nullptr, TE, TH);
        gemm_w<2><<<dim3(TH / 256, SR / 256), 512, 0, stream>>>(
            us, f2t, ocs, fb2, c2s, TH, TE);
        gather_slice<<<SC * 8, 256, 0, stream>>>(ocs, carry, out, gc0);
        save_carry<<<16, 256, 0, stream>>>(ocs, carry, SC);
    }
}

// Round 8
// 692.449 us; speedup vs baseline: 1.2510x; 1.1410x over previous
//
#include <hip/hip_runtime.h>
#include <math.h>

// PraxisNano: B=4, T=8192, H=512, E=2048, C=64, stride=32
// Inputs: float32. Output: float32. Internal: bf16 MFMA, __sinf.
// r8 = best-of-per-GEMM:
//   GEMM1 (N=2048): gemm_w 256x256 counted-vmcnt pipeline (r7; 512 WGs, full
//   machine, best per-CU MfmaUtil).
//   GEMM2 (N=512): gemm_db 128x128 256-thr drain-dbuf (r4; 512 WGs, 3 blk/CU
//   -> cross-block overlap hides the drain; best measured GEMM2).
// T2 both-sides XOR swizzle (PMC: conflicts==0) + T1 XCD swizzle in both.
#define TB 4
#define TT 8192
#define TH 512
#define TE 2048
#define NCHUNK 256
#define GCTOT 1024          // TB*NCHUNK

typedef unsigned short u16;
typedef short bf8v __attribute__((ext_vector_type(8)));   // 8 bf16 MFMA frag
typedef float f4v __attribute__((ext_vector_type(4)));    // MFMA accumulator

__device__ __forceinline__ float bu2f(u16 u) {
    unsigned int x = ((unsigned int)u) << 16; float f; __builtin_memcpy(&f, &x, 4); return f;
}
__device__ __forceinline__ u16 f2bu(float f) {
    unsigned int x; __builtin_memcpy(&x, &f, 4);
    x = x + 0x7fffu + ((x >> 16) & 1u);   // RNE
    return (u16)(x >> 16);
}

// ---------------- composite TriLinear matrix, transposed: Mt[s][t] = ((W2.tri)(W1.tri))[t][s]
__global__ __launch_bounds__(256) void make_Mt(const float* __restrict__ W1,
                                               const float* __restrict__ W2,
                                               float* __restrict__ Mt) {
    __shared__ float w1[64 * 64];
    __shared__ float w2[64 * 64];
    for (int i = threadIdx.x; i < 4096; i += 256) { w1[i] = W1[i]; w2[i] = W2[i]; }
    __syncthreads();
    for (int i = threadIdx.x; i < 4096; i += 256) {
        int t = i >> 6, s = i & 63;
        float a = 0.f;
        if (t >= s) for (int k = s; k <= t; ++k) a += w2[t * 64 + k] * w1[k * 64 + s];
        Mt[s * 64 + t] = a;
    }
}

// ---------------- transpose f32 (R x C) -> bf16 (C x R)
__global__ __launch_bounds__(256) void transpose_b(const float* __restrict__ in,
                                                   u16* __restrict__ out, int R, int C) {
    __shared__ u16 tile[64][65];
    const int bx = blockIdx.x, by = blockIdx.y;
    const int tx = threadIdx.x & 63, ty = threadIdx.x >> 6;
#pragma unroll
    for (int i = 0; i < 16; ++i) {
        int r = ty + i * 4;
        tile[r][tx] = f2bu(in[(size_t)(by * 64 + r) * C + bx * 64 + tx]);
    }
    __syncthreads();
#pragma unroll
    for (int i = 0; i < 16; ++i) {
        int r = ty + i * 4;
        out[(size_t)(bx * 64 + r) * R + by * 64 + tx] = tile[tx][r];
    }
}

// ---------------- LN1 stats per x-row (mean, rstd)
__global__ __launch_bounds__(256) void ln_stats(const float* __restrict__ x,
                                                float2* __restrict__ st) {
    const int wave = threadIdx.x >> 6, lane = threadIdx.x & 63;
    const size_t row = (size_t)blockIdx.x * 4 + wave;
    const float4* p = (const float4*)(x + row * TH);
    float4 a = p[lane * 2], b = p[lane * 2 + 1];
    float s = 0.f, q = 0.f;
    float v[8] = {a.x, a.y, a.z, a.w, b.x, b.y, b.z, b.w};
#pragma unroll
    for (int i = 0; i < 8; ++i) { s += v[i]; q += v[i] * v[i]; }
#pragma unroll
    for (int o = 32; o; o >>= 1) { s += __shfl_xor(s, o); q += __shfl_xor(q, o); }
    const float mean = s * (1.f / TH);
    float var = q * (1.f / TH) - mean * mean;
    if (var < 0.f) var = 0.f;
    if (lane == 0) st[row] = make_float2(mean, rsqrtf(var + 1e-5f));
}

// ---------------- LN2: bf16 rows in -> bf16 rows out, f32 gamma/beta
__global__ __launch_bounds__(256) void ln_rows(const u16* __restrict__ in,
                                               u16* __restrict__ out,
                                               const float* __restrict__ g,
                                               const float* __restrict__ b) {
    const int wave = threadIdx.x >> 6, lane = threadIdx.x & 63;
    const size_t row = (size_t)blockIdx.x * 4 + wave;
    uint4 raw = *((const uint4*)(in + row * TH) + lane);
    const u16* e = (const u16*)&raw;
    float v[8]; float s = 0.f, q = 0.f;
#pragma unroll
    for (int i = 0; i < 8; ++i) { v[i] = bu2f(e[i]); s += v[i]; q += v[i] * v[i]; }
#pragma unroll
    for (int o = 32; o; o >>= 1) { s += __shfl_xor(s, o); q += __shfl_xor(q, o); }
    const float mean = s * (1.f / TH);
    float var = q * (1.f / TH) - mean * mean;
    if (var < 0.f) var = 0.f;
    const float rstd = rsqrtf(var + 1e-5f);
    float4 g0 = ((const float4*)g)[lane * 2], g1 = ((const float4*)g)[lane * 2 + 1];
    float4 b0 = ((const float4*)b)[lane * 2], b1 = ((const float4*)b)[lane * 2 + 1];
    float ge[8] = {g0.x, g0.y, g0.z, g0.w, g1.x, g1.y, g1.z, g1.w};
    float be[8] = {b0.x, b0.y, b0.z, b0.w, b1.x, b1.y, b1.z, b1.w};
    u16 ov[8];
#pragma unroll
    for (int i = 0; i < 8; ++i) ov[i] = f2bu((v[i] - mean) * rstd * ge[i] + be[i]);
    *((uint4*)(out + row * TH) + lane) = *(uint4*)ov;
}

// ---------------- TriLinear for one slice (global-chunk indexed), LN1 fused via stats
__global__ __launch_bounds__(256) void trilinear_f(const float* __restrict__ x,
                                                   const float2* __restrict__ st,
                                                   const float* __restrict__ g,
                                                   const float* __restrict__ bb,
                                                   const float* __restrict__ Mt,
                                                   u16* __restrict__ c2s,
                                                   int gc0) {
    const int ln = blockIdx.x;
    const int gc = gc0 + ln;
    const int b = gc >> 8, n = gc & 255;
    const int h = (blockIdx.y << 8) + threadIdx.x;
    const int base = n * 32;
    const float gh = g[h], bh = bb[h];
    float acc[64];
#pragma unroll
    for (int t = 0; t < 64; ++t) acc[t] = 0.f;
    for (int s = 0; s < 64; ++s) {
        int pos = base + s; if (pos > TT - 1) pos = TT - 1;
        const size_t ro = (size_t)b * TT + pos;
        const float2 mr = st[ro];
        const float cn = (x[ro * TH + h] - mr.x) * mr.y * gh + bh;
        const float* m = Mt + s * 64;
#pragma unroll
        for (int t = 0; t < 64; ++t) acc[t] += m[t] * cn;
    }
#pragma unroll
    for (int t = 0; t < 64; ++t) {
        int pos = base + t; if (pos > TT - 1) pos = TT - 1;
        const float resid = x[((size_t)b * TT + pos) * TH + h];
        c2s[(size_t)(ln * 64 + t) * TH + h] = f2bu(acc[t] + resid);
    }
}

// ---------------- GEMM1: 256x256, per-wave 128x64, counted-vmcnt dbuf (r7)
// MODE 1: C = __sinf(acc + bias);  MODE 2: C = acc + bias + addp
template <int MODE>
__global__ __launch_bounds__(512, 2) void gemm_w(const u16* __restrict__ A,    // M x K bf16
                                                 const u16* __restrict__ Bt,   // N x K bf16
                                                 u16* __restrict__ C,          // M x N bf16
                                                 const float* __restrict__ bias,
                                                 const u16* __restrict__ addp,
                                                 int N, int K) {
    __shared__ __attribute__((aligned(16))) u16 lA[2][256 * 64];   // 64 KiB
    __shared__ __attribute__((aligned(16))) u16 lB[2][256 * 64];   // 64 KiB
    const int tid = threadIdx.x;
    const int wave = tid >> 6;             // 0..7
    const int lane = tid & 63;
    const int wr = wave >> 2;              // 0..1 (M): rows wr*128..+128
    const int wc = wave & 3;               // 0..3 (N): cols wc*64..+64
    const int fr = lane & 15;
    const int fq = (lane >> 4) << 3;       // 0,8,16,24 (u16)
    const int s8 = (fr & 7) << 3;          // swizzle XOR (u16)

    // T1: XCD-chunked block swizzle (bijective when nwg%8==0)
    int bx = blockIdx.x, by = blockIdx.y;
    const int gx = gridDim.x;
    const int nwg = gx * (int)gridDim.y;
    if ((nwg & 7) == 0) {
        const int bid = by * gx + bx;
        const int swz = (bid & 7) * (nwg >> 3) + (bid >> 3);
        bx = swz % gx; by = swz / gx;
    }
    const int bm = by << 8;
    const int bn = bx << 8;

    // staging addresses: row srow (+i*64), source chunk XOR'ed by row&7
    const int srow = tid >> 3;                          // 0..63
    const int gch = ((tid & 7) ^ (srow & 7)) << 3;      // u16 offset
    const u16* pa = A + (size_t)(bm + srow) * K + gch;
    const u16* pb = Bt + (size_t)(bn + srow) * K + gch;
    const int ldsw = wave << 9;                         // wave-uniform base (u16)

    const int NT = K >> 6;
    f4v acc[8][4] = {};

    auto stage = [&](int t, int buf) {
        const size_t ko = (size_t)t << 6;
#pragma unroll
        for (int i = 0; i < 4; ++i)
            __builtin_amdgcn_global_load_lds(
                (const __attribute__((address_space(1))) void*)(pa + (size_t)(i * 64) * K + ko),
                (__attribute__((address_space(3))) void*)(&lA[buf][(i << 12) + ldsw]), 16, 0, 0);
#pragma unroll
        for (int i = 0; i < 4; ++i)
            __builtin_amdgcn_global_load_lds(
                (const __attribute__((address_space(1))) void*)(pb + (size_t)(i * 64) * K + ko),
                (__attribute__((address_space(3))) void*)(&lB[buf][(i << 12) + ldsw]), 16, 0, 0);
    };

    // prologue: tiles 0,1 in flight (16 loads); counted wait confirms tile 0.
    stage(0, 0);
    stage(1, 1);
    asm volatile("s_waitcnt vmcnt(8)" ::: "memory");
    asm volatile("s_barrier" ::: "memory");

    const int arow0 = (wr << 7) + fr;      // + mi*16
    const int brow0 = (wc << 6) + fr;      // + ni*16
    const int c0 = fq ^ s8;                // slice ks=0 swizzled col (u16)
    const int c1 = (32 + fq) ^ s8;         // slice ks=32 (XOR on chunk bits)

    for (int t = 0; t < NT; ++t) {
        const int buf = t & 1;
        const u16* la = lA[buf];
        const u16* lb = lB[buf];
        // ---- read ALL fragments of this tile (24 x ds_read_b128)
        bf8v af[8][2], bf[4][2];
#pragma unroll
        for (int mi = 0; mi < 8; ++mi) {
            af[mi][0] = *(const bf8v*)(la + ((arow0 + (mi << 4)) << 6) + c0);
            af[mi][1] = *(const bf8v*)(la + ((arow0 + (mi << 4)) << 6) + c1);
        }
#pragma unroll
        for (int ni = 0; ni < 4; ++ni) {
            bf[ni][0] = *(const bf8v*)(lb + ((brow0 + (ni << 4)) << 6) + c0);
            bf[ni][1] = *(const bf8v*)(lb + ((brow0 + (ni << 4)) << 6) + c1);
        }
        asm volatile("s_waitcnt lgkmcnt(0)" ::: "memory");
        __builtin_amdgcn_sched_barrier(0);
        asm volatile("s_barrier" ::: "memory");          // all waves done reading buf
        if (t + 2 < NT) stage(t + 2, buf);               // overwrite freed buffer, async
        // ---- 64 MFMA
        __builtin_amdgcn_s_setprio(1);
#pragma unroll
        for (int ks = 0; ks < 2; ++ks)
#pragma unroll
            for (int mi = 0; mi < 8; ++mi)
#pragma unroll
                for (int ni = 0; ni < 4; ++ni)
                    acc[mi][ni] = __builtin_amdgcn_mfma_f32_16x16x32_bf16(af[mi][ks], bf[ni][ks], acc[mi][ni], 0, 0, 0);
        __builtin_amdgcn_s_setprio(0);
        // ---- confirm tile t+1 (counted), publish
        if (t + 1 < NT) {
            if (t + 2 < NT) asm volatile("s_waitcnt vmcnt(8)" ::: "memory");
            else            asm volatile("s_waitcnt vmcnt(0)" ::: "memory");
            asm volatile("s_barrier" ::: "memory");
        }
    }

    // ---- epilogue: C/D layout col=lane&15, row=(lane>>4)*4+r (m89/m91)
    const int rq = (lane >> 4) << 2;
#pragma unroll
    for (int mi = 0; mi < 8; ++mi) {
#pragma unroll
        for (int ni = 0; ni < 4; ++ni) {
            const int col = bn + (wc << 6) + (ni << 4) + fr;
            const float bv = bias[col];
#pragma unroll
            for (int r = 0; r < 4; ++r) {
                const int row = bm + (wr << 7) + (mi << 4) + rq + r;
                float v = acc[mi][ni][r] + bv;
                if (MODE == 1) v = __sinf(v);
                else v += bu2f(addp[(size_t)row * N + col]);
                C[(size_t)row * N + col] = f2bu(v);
            }
        }
    }
}

// ---------------- GEMM2: 128x128, 256 thr, drain-dbuf (r4's gemm_db, verified)
// MODE 1: C = __sinf(acc + bias);  MODE 2: C = acc + bias + addp
template <int MODE>
__global__ __launch_bounds__(256) void gemm_db(const u16* __restrict__ A,    // M x K bf16
                                               const u16* __restrict__ Bt,   // N x K bf16
                                               u16* __restrict__ C,          // M x N bf16
                                               const float* __restrict__ bias,
                                               const u16* __restrict__ addp,
                                               int N, int K) {
    __shared__ __attribute__((aligned(16))) u16 lA[2][128 * 64];
    __shared__ __attribute__((aligned(16))) u16 lB[2][128 * 64];
    const int tid = threadIdx.x;
    const int wave = tid >> 6;
    const int lane = tid & 63;
    const int wr = wave >> 1;
    const int wc = wave & 1;
    const int fr = lane & 15;
    const int fq = (lane >> 4) << 3;       // 0,8,16,24 (u16)
    const int s8 = (fr & 7) << 3;          // swizzle XOR (u16)

    // T1: XCD-chunked block swizzle
    int bx = blockIdx.x, by = blockIdx.y;
    const int gx = gridDim.x;
    const int nwg = gx * (int)gridDim.y;
    if ((nwg & 7) == 0) {
        const int bid = by * gx + bx;
        const int swz = (bid & 7) * (nwg >> 3) + (bid >> 3);
        bx = swz % gx; by = swz / gx;
    }
    const int bm = by << 7;
    const int bn = bx << 7;

    // staging addresses: row srow (+i*32), source chunk XOR'ed by row&7
    const int srow = tid >> 3;                          // 0..31
    const int gch = ((tid & 7) ^ (srow & 7)) << 3;      // u16 offset
    const u16* pa = A + (size_t)(bm + srow) * K + gch;
    const u16* pb = Bt + (size_t)(bn + srow) * K + gch;
    const int ldsw = wave << 9;                         // wave base within a 32-row group (u16)

    const int NT = K >> 6;
    f4v acc[4][4] = {};

    auto stage = [&](int t, int buf) {
        const int ko = t << 6;
#pragma unroll
        for (int i = 0; i < 4; ++i) {
            __builtin_amdgcn_global_load_lds(
                (const __attribute__((address_space(1))) void*)(pa + (size_t)(i * 32) * K + ko),
                (__attribute__((address_space(3))) void*)(&lA[buf][(i << 11) + ldsw]), 16, 0, 0);
            __builtin_amdgcn_global_load_lds(
                (const __attribute__((address_space(1))) void*)(pb + (size_t)(i * 32) * K + ko),
                (__attribute__((address_space(3))) void*)(&lB[buf][(i << 11) + ldsw]), 16, 0, 0);
        }
    };

    stage(0, 0);
    __syncthreads();

    const int arow0 = (wr << 6) + fr;      // + mi*16
    const int brow0 = (wc << 6) + fr;      // + ni*16
    const int c0 = fq ^ s8;                // slice ks=0 swizzled col (u16)
    const int c1 = (32 + fq) ^ s8;         // slice ks=32 (XOR on chunk bits)

    int buf = 0;
    for (int t = 0; t < NT; ++t) {
        if (t + 1 < NT) stage(t + 1, buf ^ 1);   // prefetch overlaps this tile's compute
        const u16* la = lA[buf];
        const u16* lb = lB[buf];
#pragma unroll
        for (int half = 0; half < 2; ++half) {
            const int cc = half ? c1 : c0;
            bf8v af[4], bfv[4];
#pragma unroll
            for (int mi = 0; mi < 4; ++mi)
                af[mi] = *(const bf8v*)(la + ((arow0 + (mi << 4)) << 6) + cc);
#pragma unroll
            for (int ni = 0; ni < 4; ++ni)
                bfv[ni] = *(const bf8v*)(lb + ((brow0 + (ni << 4)) << 6) + cc);
#pragma unroll
            for (int mi = 0; mi < 4; ++mi)
#pragma unroll
                for (int ni = 0; ni < 4; ++ni)
                    acc[mi][ni] = __builtin_amdgcn_mfma_f32_16x16x32_bf16(af[mi], bfv[ni], acc[mi][ni], 0, 0, 0);
        }
        __syncthreads();                         // drains prefetch + frees buf for overwrite
        buf ^= 1;
    }

    // ---- epilogue: C/D layout col=lane&15, row=(lane>>4)*4+r (m89/m91)
    const int rq = (lane >> 4) << 2;
#pragma unroll
    for (int mi = 0; mi < 4; ++mi) {
#pragma unroll
        for (int ni = 0; ni < 4; ++ni) {
            const int col = bn + (wc << 6) + (ni << 4) + fr;
            const float bv = bias[col];
#pragma unroll
            for (int r = 0; r < 4; ++r) {
                const int row = bm + (wr << 6) + (mi << 4) + rq + r;
                float v = acc[mi][ni][r] + bv;
                if (MODE == 1) v = __sinf(v);
                else v += bu2f(addp[(size_t)row * N + col]);
                C[(size_t)row * N + col] = f2bu(v);
            }
        }
    }
}

// ---------------- per-slice gather -> FLOAT32 output (linear position mapping)
__global__ __launch_bounds__(256) void gather_slice(const u16* __restrict__ ocs,
                                                    const u16* __restrict__ carry,
                                                    float* __restrict__ out,
                                                    int gc0) {
    const int idx = blockIdx.x * 256 + threadIdx.x;   // vec8 id within slice
    const int h8 = idx & 63;                          // TH/8
    const int prow = idx >> 6;                        // 0 .. SC*32-1
    const int ap = gc0 * 32 + prow;                   // linear (b,t) position index
    const int b = ap >> 13, t = ap & 8191;
    const int n = t >> 5, c = t & 31;
    const int ln = (b << 8) + n - gc0;                // covering chunk, slice-local
    uint4 r1 = *((const uint4*)ocs + (size_t)(ln * 64 + c) * 64 + h8);
    const u16* e1 = (const u16*)&r1;
    float ov[8];
    if (t < 32) {
#pragma unroll
        for (int i = 0; i < 8; ++i) ov[i] = bu2f(e1[i]);
    } else {
        uint4 r0;
        if (ln == 0) r0 = *((const uint4*)carry + (size_t)(c + 32) * 64 + h8);
        else         r0 = *((const uint4*)ocs + (size_t)((ln - 1) * 64 + c + 32) * 64 + h8);
        const u16* e0 = (const u16*)&r0;
#pragma unroll
        for (int i = 0; i < 8; ++i) ov[i] = 0.5f * (bu2f(e1[i]) + bu2f(e0[i]));
    }
    float4* dst = (float4*)(out + (size_t)ap * TH + h8 * 8);
    dst[0] = make_float4(ov[0], ov[1], ov[2], ov[3]);
    dst[1] = make_float4(ov[4], ov[5], ov[6], ov[7]);
}

// ---------------- save last chunk of slice for next slice's boundary
__global__ __launch_bounds__(256) void save_carry(const u16* __restrict__ ocs,
                                                  u16* __restrict__ carry, int SC) {
    const int i = blockIdx.x * 256 + threadIdx.x;     // uint4 id, 4096 total
    ((uint4*)carry)[i] = ((const uint4*)(ocs + (size_t)(SC - 1) * 64 * TH))[i];
}

extern "C" void kernel_launch(void* const* d_in, const int* in_sizes, int n_in,
                              void* d_out, int out_size, void* d_ws, size_t ws_size,
                              hipStream_t stream) {
    const float* x   = (const float*)d_in[0];
    const float* g1  = (const float*)d_in[1];
    const float* b1  = (const float*)d_in[2];
    const float* W1  = (const float*)d_in[3];
    const float* W2  = (const float*)d_in[4];
    const float* g2  = (const float*)d_in[5];
    const float* b2  = (const float*)d_in[6];
    const float* fw1 = (const float*)d_in[7];
    const float* fb1 = (const float*)d_in[8];
    const float* fw2 = (const float*)d_in[9];
    const float* fb2 = (const float*)d_in[10];
    float* out = (float*)d_out;
    char* ws = (char*)d_ws;

    size_t o = 0;
    auto take = [&](size_t n) { size_t r = o; o = (o + n + 255) & ~(size_t)255; return r; };
    float*  Mt    = (float*) (ws + take(64 * 64 * 4));
    u16*    f1t   = (u16*)   (ws + take((size_t)TE * TH * 2));
    u16*    f2t   = (u16*)   (ws + take((size_t)TH * TE * 2));
    float2* st1   = (float2*)(ws + take((size_t)TB * TT * 8));
    u16*    carry = (u16*)   (ws + take((size_t)64 * TH * 2));
    const size_t fixed = o;

    // Adaptive slice size (global chunks per slice). Min 4 so SR is a multiple
    // of 256 (gemm_w uses 256-row tiles); cap 256 so us stays L3-resident.
    int SC = 4;
    for (int cand = 256; cand >= 4; cand >>= 1) {
        size_t per = (size_t)cand * 64 * (TH * 2 * 3 + TE * 2) + 4 * 256;
        if (fixed + per <= ws_size) { SC = cand; break; }
    }
    u16* c2s = (u16*)(ws + take((size_t)SC * 64 * TH * 2));
    u16* h2s = (u16*)(ws + take((size_t)SC * 64 * TH * 2));
    u16* ocs = (u16*)(ws + take((size_t)SC * 64 * TH * 2));
    u16* us  = (u16*)(ws + take((size_t)SC * 64 * TE * 2));
    const int SR = SC * 64;

    make_Mt<<<1, 256, 0, stream>>>(W1, W2, Mt);
    transpose_b<<<dim3(TE / 64, TH / 64), 256, 0, stream>>>(fw1, f1t, TH, TE);
    transpose_b<<<dim3(TH / 64, TE / 64), 256, 0, stream>>>(fw2, f2t, TE, TH);
    ln_stats<<<(TB * TT) / 4, 256, 0, stream>>>(x, st1);

    for (int gc0 = 0; gc0 < GCTOT; gc0 += SC) {
        trilinear_f<<<dim3(SC, TH / 256), 256, 0, stream>>>(x, st1, g1, b1, Mt, c2s, gc0);
        ln_rows<<<SR / 4, 256, 0, stream>>>(c2s, h2s, g2, b2);
        gemm_w<1><<<dim3(TE / 256, SR / 256), 512, 0, stream>>>(
            h2s, f1t, us, fb1, (const u16*)nullptr, TE, TH);
        gemm_db<2><<<dim3(TH / 128, SR / 128), 256, 0, stream>>>(
            us, f2t, ocs, fb2, c2s, TH, TE);
        gather_slice<<<SC * 8, 256, 0, stream>>>(ocs, carry, out, gc0);
        save_carry<<<16, 256, 0, stream>>>(ocs, carry, SC);
    }
}